// Round 7
// baseline (111.919 us; speedup 1.0000x reference)
//
#include <hip/hip_runtime.h>
#include <hip/hip_bf16.h>
#include <math.h>

// MoE gate: logits = x[16384,8192] @ W[8,8192]^T ; top-2 softmax scattered
// into dense [16384,8] fp32 output. Memory-bound on streaming x (512 MiB).
//
// R6: R3 structure (split-D, 256-thread blocks, stage-once, barrier-free
// stream, slice<->XCD pinning) with TPW=2: 8 tokens/block, grid 16384.
// Halves the per-block butterfly epilogue (96 shuffles) and doubles the
// number of independent blocks for overlap. R4/R5 proved bigger/longer
// blocks regress; this goes the opposite way.

#define D 8192
#define NE 8
#define NTOK 16384
#define CHUNK 1024
#define SLICES (D / CHUNK)      // 8
#define TPW 2                   // tokens per wave
#define TPB (TPW * 4)           // 8 tokens per block (4 waves)

typedef float f32x4 __attribute__((ext_vector_type(4)));

__global__ __launch_bounds__(256) void gate_partial(const float* __restrict__ x,
                                                    const float* __restrict__ W,
                                                    float* __restrict__ ws) {
    __shared__ float Wl[NE][CHUNK];   // 32 KiB
    const int tid   = threadIdx.x;
    const int wave  = tid >> 6;
    const int lane  = tid & 63;
    const int slice = blockIdx.x & (SLICES - 1);
    const int group = blockIdx.x >> 3;
    const int f0    = slice * CHUNK;

    // stage this slice's W once: 8 experts x 1024 floats (32 KiB)
#pragma unroll
    for (int e = 0; e < NE; ++e)
        *(f32x4*)&Wl[e][tid * 4] = *(const f32x4*)&W[e * D + f0 + tid * 4];
    __syncthreads();

    const int tokBase = group * TPB + wave * TPW;
    const float* xb = x + (size_t)tokBase * D + f0;

    float acc[TPW][NE];
#pragma unroll
    for (int t = 0; t < TPW; ++t)
#pragma unroll
        for (int e = 0; e < NE; ++e) acc[t][e] = 0.0f;

#pragma unroll
    for (int p = 0; p < CHUNK / 256; ++p) {     // 4 passes of 256 features
        const int f = p * 256 + lane * 4;
        f32x4 xv[TPW];
#pragma unroll
        for (int t = 0; t < TPW; ++t)
            xv[t] = *(const f32x4*)&xb[(size_t)t * D + f];
#pragma unroll
        for (int e = 0; e < NE; ++e) {
            f32x4 wv = *(const f32x4*)&Wl[e][f];
#pragma unroll
            for (int t = 0; t < TPW; ++t) {
                acc[t][e] += xv[t].x * wv.x;
                acc[t][e] += xv[t].y * wv.y;
                acc[t][e] += xv[t].z * wv.z;
                acc[t][e] += xv[t].w * wv.w;
            }
        }
    }

    // wave-wide butterfly reduction (wave = 64)
#pragma unroll
    for (int t = 0; t < TPW; ++t)
#pragma unroll
        for (int e = 0; e < NE; ++e) {
            float v = acc[t][e];
#pragma unroll
            for (int off = 32; off; off >>= 1) v += __shfl_xor(v, off, 64);
            acc[t][e] = v;
        }

    // lanes 0..7 write one expert each (select chain keeps acc statically
    // indexed -- no scratch)
#pragma unroll
    for (int t = 0; t < TPW; ++t) {
        float v = 0.0f;
#pragma unroll
        for (int e = 0; e < NE; ++e) v = (lane == e) ? acc[t][e] : v;
        if (lane < NE)
            ws[((size_t)slice * NTOK + tokBase + t) * NE + lane] = v;
    }
}

__global__ __launch_bounds__(256) void gate_final(const float* __restrict__ ws,
                                                  float* __restrict__ out) {
    const int t = blockIdx.x * 256 + threadIdx.x;   // one token per thread
    float s[NE];
#pragma unroll
    for (int e = 0; e < NE; ++e) s[e] = 0.0f;
#pragma unroll
    for (int sl = 0; sl < SLICES; ++sl) {
        const float* p = &ws[((size_t)sl * NTOK + t) * NE];
        f32x4 a = *(const f32x4*)p;
        f32x4 b = *(const f32x4*)(p + 4);
        s[0] += a.x; s[1] += a.y; s[2] += a.z; s[3] += a.w;
        s[4] += b.x; s[5] += b.y; s[6] += b.z; s[7] += b.w;
    }
    // top-2 (strict > keeps lowest index on ties, matching jax.lax.top_k)
    float b1 = s[0]; int i1 = 0;
#pragma unroll
    for (int e = 1; e < NE; ++e)
        if (s[e] > b1) { b1 = s[e]; i1 = e; }
    float b2 = -INFINITY; int i2 = 0;
#pragma unroll
    for (int e = 0; e < NE; ++e)
        if (e != i1 && s[e] > b2) { b2 = s[e]; i2 = e; }
    float q  = expf(b2 - b1);        // <= 1
    float p1 = 1.0f / (1.0f + q);
    float p2 = q * p1;

    f32x4 o0, o1;
    o0.x = (i1 == 0) ? p1 : ((i2 == 0) ? p2 : 0.0f);
    o0.y = (i1 == 1) ? p1 : ((i2 == 1) ? p2 : 0.0f);
    o0.z = (i1 == 2) ? p1 : ((i2 == 2) ? p2 : 0.0f);
    o0.w = (i1 == 3) ? p1 : ((i2 == 3) ? p2 : 0.0f);
    o1.x = (i1 == 4) ? p1 : ((i2 == 4) ? p2 : 0.0f);
    o1.y = (i1 == 5) ? p1 : ((i2 == 5) ? p2 : 0.0f);
    o1.z = (i1 == 6) ? p1 : ((i2 == 6) ? p2 : 0.0f);
    o1.w = (i1 == 7) ? p1 : ((i2 == 7) ? p2 : 0.0f);
    *(f32x4*)&out[(size_t)t * NE]     = o0;
    *(f32x4*)&out[(size_t)t * NE + 4] = o1;
}

// ---- fallback: fused single-kernel path, used if ws too small ----
__global__ __launch_bounds__(256) void gate_fused(const float* __restrict__ x,
                                                  const float* __restrict__ W,
                                                  float* __restrict__ out) {
    __shared__ float Wl[NE][CHUNK];
    const int tid = threadIdx.x, wave = tid >> 6, lane = tid & 63;
    const int tokBase = blockIdx.x * 16 + wave * 4;

    float acc[4][NE];
#pragma unroll
    for (int t = 0; t < 4; ++t)
#pragma unroll
        for (int e = 0; e < NE; ++e) acc[t][e] = 0.0f;

    for (int ch = 0; ch < SLICES; ++ch) {
        __syncthreads();
#pragma unroll
        for (int e = 0; e < NE; ++e)
            *(f32x4*)&Wl[e][tid * 4] = *(const f32x4*)&W[e * D + ch * CHUNK + tid * 4];
        __syncthreads();
#pragma unroll
        for (int p = 0; p < CHUNK / 256; ++p) {
            const int f = p * 256 + lane * 4;
            f32x4 xv[4];
#pragma unroll
            for (int t = 0; t < 4; ++t)
                xv[t] = *(const f32x4*)&x[(size_t)(tokBase + t) * D + ch * CHUNK + f];
#pragma unroll
            for (int e = 0; e < NE; ++e) {
                f32x4 wv = *(const f32x4*)&Wl[e][f];
#pragma unroll
                for (int t = 0; t < 4; ++t) {
                    acc[t][e] += xv[t].x * wv.x;
                    acc[t][e] += xv[t].y * wv.y;
                    acc[t][e] += xv[t].z * wv.z;
                    acc[t][e] += xv[t].w * wv.w;
                }
            }
        }
    }
#pragma unroll
    for (int t = 0; t < 4; ++t)
#pragma unroll
        for (int e = 0; e < NE; ++e) {
            float v = acc[t][e];
#pragma unroll
            for (int off = 32; off; off >>= 1) v += __shfl_xor(v, off, 64);
            acc[t][e] = v;
        }
#pragma unroll
    for (int t = 0; t < 4; ++t) {
        float b1 = acc[t][0]; int i1 = 0;
#pragma unroll
        for (int e = 1; e < NE; ++e)
            if (acc[t][e] > b1) { b1 = acc[t][e]; i1 = e; }
        float b2 = -INFINITY; int i2 = 0;
#pragma unroll
        for (int e = 0; e < NE; ++e)
            if (e != i1 && acc[t][e] > b2) { b2 = acc[t][e]; i2 = e; }
        float q  = expf(b2 - b1);
        float p1 = 1.0f / (1.0f + q);
        float p2 = q * p1;
        if (lane < NE)
            out[(size_t)(tokBase + t) * NE + lane] =
                (lane == i1) ? p1 : ((lane == i2) ? p2 : 0.0f);
    }
}

extern "C" void kernel_launch(void* const* d_in, const int* in_sizes, int n_in,
                              void* d_out, int out_size, void* d_ws, size_t ws_size,
                              hipStream_t stream) {
    const float* x = (const float*)d_in[0];
    const float* W = (const float*)d_in[1];
    float* out = (float*)d_out;

    const size_t ws_need = (size_t)SLICES * NTOK * NE * sizeof(float);  // 4 MiB
    if (ws_size >= ws_need) {
        float* ws = (float*)d_ws;
        const int grid1 = (NTOK / TPB) * SLICES;   // 16384
        gate_partial<<<grid1, 256, 0, stream>>>(x, W, ws);
        gate_final<<<NTOK / 256, 256, 0, stream>>>(ws, out);
    } else {
        gate_fused<<<NTOK / 16, 256, 0, stream>>>(x, W, out);
    }
}

// Round 8
// 96.414 us; speedup vs baseline: 1.1608x; 1.1608x over previous
//
#include <hip/hip_runtime.h>
#include <hip/hip_bf16.h>
#include <math.h>

// MoE gate: logits = x[16384,8192] @ W[8,8192]^T ; top-2 softmax scattered
// into dense [16384,8] fp32 output. Memory-bound on streaming x (512 MiB).
//
// R7: R3 exactly (split-D, 256-thread blocks, TPW=4, stage-once,
// barrier-free stream, slice<->XCD pinning — the 102 us local optimum),
// plus ONE change: nontemporal x loads. x is streamed once and never
// re-read; nt bypasses L2/L3 line allocation for it. W is LDS-resident so
// R1/R2's confound (nt protecting W residency) is gone — this isolates
// the stream-bypass effect.

#define D 8192
#define NE 8
#define NTOK 16384
#define CHUNK 1024
#define SLICES (D / CHUNK)      // 8
#define TPW 4                   // tokens per wave
#define TPB 16                  // 4 waves * TPW

typedef float f32x4 __attribute__((ext_vector_type(4)));

__global__ __launch_bounds__(256) void gate_partial(const float* __restrict__ x,
                                                    const float* __restrict__ W,
                                                    float* __restrict__ ws) {
    __shared__ float Wl[NE][CHUNK];   // 32 KiB
    const int tid   = threadIdx.x;
    const int wave  = tid >> 6;
    const int lane  = tid & 63;
    const int slice = blockIdx.x & (SLICES - 1);
    const int group = blockIdx.x >> 3;
    const int f0    = slice * CHUNK;

    // stage this slice's W once: 8 experts x 1024 floats (32 KiB)
#pragma unroll
    for (int e = 0; e < NE; ++e)
        *(f32x4*)&Wl[e][tid * 4] = *(const f32x4*)&W[e * D + f0 + tid * 4];
    __syncthreads();

    const int tokBase = group * TPB + wave * TPW;
    const float* xb = x + (size_t)tokBase * D + f0;

    float acc[TPW][NE];
#pragma unroll
    for (int t = 0; t < TPW; ++t)
#pragma unroll
        for (int e = 0; e < NE; ++e) acc[t][e] = 0.0f;

#pragma unroll
    for (int p = 0; p < CHUNK / 256; ++p) {     // 4 passes of 256 features
        const int f = p * 256 + lane * 4;
        f32x4 xv[TPW];
#pragma unroll
        for (int t = 0; t < TPW; ++t)
            xv[t] = __builtin_nontemporal_load((const f32x4*)&xb[(size_t)t * D + f]);
#pragma unroll
        for (int e = 0; e < NE; ++e) {
            f32x4 wv = *(const f32x4*)&Wl[e][f];
#pragma unroll
            for (int t = 0; t < TPW; ++t) {
                acc[t][e] += xv[t].x * wv.x;
                acc[t][e] += xv[t].y * wv.y;
                acc[t][e] += xv[t].z * wv.z;
                acc[t][e] += xv[t].w * wv.w;
            }
        }
    }

    // wave-wide butterfly reduction (wave = 64)
#pragma unroll
    for (int t = 0; t < TPW; ++t)
#pragma unroll
        for (int e = 0; e < NE; ++e) {
            float v = acc[t][e];
#pragma unroll
            for (int off = 32; off; off >>= 1) v += __shfl_xor(v, off, 64);
            acc[t][e] = v;
        }

    // lanes 0..7 write one expert each (select chain keeps acc statically
    // indexed -- no scratch)
#pragma unroll
    for (int t = 0; t < TPW; ++t) {
        float v = 0.0f;
#pragma unroll
        for (int e = 0; e < NE; ++e) v = (lane == e) ? acc[t][e] : v;
        if (lane < NE)
            ws[((size_t)slice * NTOK + tokBase + t) * NE + lane] = v;
    }
}

__global__ __launch_bounds__(256) void gate_final(const float* __restrict__ ws,
                                                  float* __restrict__ out) {
    const int t = blockIdx.x * 256 + threadIdx.x;   // one token per thread
    float s[NE];
#pragma unroll
    for (int e = 0; e < NE; ++e) s[e] = 0.0f;
#pragma unroll
    for (int sl = 0; sl < SLICES; ++sl) {
        const float* p = &ws[((size_t)sl * NTOK + t) * NE];
        f32x4 a = *(const f32x4*)p;
        f32x4 b = *(const f32x4*)(p + 4);
        s[0] += a.x; s[1] += a.y; s[2] += a.z; s[3] += a.w;
        s[4] += b.x; s[5] += b.y; s[6] += b.z; s[7] += b.w;
    }
    // top-2 (strict > keeps lowest index on ties, matching jax.lax.top_k)
    float b1 = s[0]; int i1 = 0;
#pragma unroll
    for (int e = 1; e < NE; ++e)
        if (s[e] > b1) { b1 = s[e]; i1 = e; }
    float b2 = -INFINITY; int i2 = 0;
#pragma unroll
    for (int e = 0; e < NE; ++e)
        if (e != i1 && s[e] > b2) { b2 = s[e]; i2 = e; }
    float q  = expf(b2 - b1);        // <= 1
    float p1 = 1.0f / (1.0f + q);
    float p2 = q * p1;

    f32x4 o0, o1;
    o0.x = (i1 == 0) ? p1 : ((i2 == 0) ? p2 : 0.0f);
    o0.y = (i1 == 1) ? p1 : ((i2 == 1) ? p2 : 0.0f);
    o0.z = (i1 == 2) ? p1 : ((i2 == 2) ? p2 : 0.0f);
    o0.w = (i1 == 3) ? p1 : ((i2 == 3) ? p2 : 0.0f);
    o1.x = (i1 == 4) ? p1 : ((i2 == 4) ? p2 : 0.0f);
    o1.y = (i1 == 5) ? p1 : ((i2 == 5) ? p2 : 0.0f);
    o1.z = (i1 == 6) ? p1 : ((i2 == 6) ? p2 : 0.0f);
    o1.w = (i1 == 7) ? p1 : ((i2 == 7) ? p2 : 0.0f);
    *(f32x4*)&out[(size_t)t * NE]     = o0;
    *(f32x4*)&out[(size_t)t * NE + 4] = o1;
}

// ---- fallback: fused single-kernel path, used if ws too small ----
__global__ __launch_bounds__(256) void gate_fused(const float* __restrict__ x,
                                                  const float* __restrict__ W,
                                                  float* __restrict__ out) {
    __shared__ float Wl[NE][CHUNK];
    const int tid = threadIdx.x, wave = tid >> 6, lane = tid & 63;
    const int tokBase = blockIdx.x * 16 + wave * 4;

    float acc[4][NE];
#pragma unroll
    for (int t = 0; t < 4; ++t)
#pragma unroll
        for (int e = 0; e < NE; ++e) acc[t][e] = 0.0f;

    for (int ch = 0; ch < SLICES; ++ch) {
        __syncthreads();
#pragma unroll
        for (int e = 0; e < NE; ++e)
            *(f32x4*)&Wl[e][tid * 4] = *(const f32x4*)&W[e * D + ch * CHUNK + tid * 4];
        __syncthreads();
#pragma unroll
        for (int p = 0; p < CHUNK / 256; ++p) {
            const int f = p * 256 + lane * 4;
            f32x4 xv[4];
#pragma unroll
            for (int t = 0; t < 4; ++t)
                xv[t] = *(const f32x4*)&x[(size_t)(tokBase + t) * D + ch * CHUNK + f];
#pragma unroll
            for (int e = 0; e < NE; ++e) {
                f32x4 wv = *(const f32x4*)&Wl[e][f];
#pragma unroll
                for (int t = 0; t < 4; ++t) {
                    acc[t][e] += xv[t].x * wv.x;
                    acc[t][e] += xv[t].y * wv.y;
                    acc[t][e] += xv[t].z * wv.z;
                    acc[t][e] += xv[t].w * wv.w;
                }
            }
        }
    }
#pragma unroll
    for (int t = 0; t < 4; ++t)
#pragma unroll
        for (int e = 0; e < NE; ++e) {
            float v = acc[t][e];
#pragma unroll
            for (int off = 32; off; off >>= 1) v += __shfl_xor(v, off, 64);
            acc[t][e] = v;
        }
#pragma unroll
    for (int t = 0; t < 4; ++t) {
        float b1 = acc[t][0]; int i1 = 0;
#pragma unroll
        for (int e = 1; e < NE; ++e)
            if (acc[t][e] > b1) { b1 = acc[t][e]; i1 = e; }
        float b2 = -INFINITY; int i2 = 0;
#pragma unroll
        for (int e = 0; e < NE; ++e)
            if (e != i1 && acc[t][e] > b2) { b2 = acc[t][e]; i2 = e; }
        float q  = expf(b2 - b1);
        float p1 = 1.0f / (1.0f + q);
        float p2 = q * p1;
        if (lane < NE)
            out[(size_t)(tokBase + t) * NE + lane] =
                (lane == i1) ? p1 : ((lane == i2) ? p2 : 0.0f);
    }
}

extern "C" void kernel_launch(void* const* d_in, const int* in_sizes, int n_in,
                              void* d_out, int out_size, void* d_ws, size_t ws_size,
                              hipStream_t stream) {
    const float* x = (const float*)d_in[0];
    const float* W = (const float*)d_in[1];
    float* out = (float*)d_out;

    const size_t ws_need = (size_t)SLICES * NTOK * NE * sizeof(float);  // 4 MiB
    if (ws_size >= ws_need) {
        float* ws = (float*)d_ws;
        const int grid1 = (NTOK / TPB) * SLICES;   // 8192
        gate_partial<<<grid1, 256, 0, stream>>>(x, W, ws);
        gate_final<<<NTOK / 256, 256, 0, stream>>>(ws, out);
    } else {
        gate_fused<<<NTOK / 16, 256, 0, stream>>>(x, W, out);
    }
}